// Round 6
// baseline (41940.842 us; speedup 1.0000x reference)
//
#include <hip/hip_runtime.h>
#include <math.h>
#include <stdio.h>

#ifndef JAX_PARTITIONABLE
#define JAX_PARTITIONABLE 1
#endif

namespace {

constexpr int B  = 512;
constexpr int S  = 256;
constexpr int E  = 256;
constexpr int H  = 512;
constexpr int V  = 32000;
constexpr int G3 = 3 * H;      // 1536
constexpr int VBLK = 64;       // v-tile (also the softmax chunk width)
constexpr int BBLK = 256;      // b-tile
constexpr int NCH  = V / VBLK; // 500 chunks
constexpr int NDMAX = 96;      // max non-drawn rows per step (mean<=47)

typedef __bf16 bf16x8 __attribute__((ext_vector_type(8)));
typedef float  f32x4  __attribute__((ext_vector_type(4)));
typedef unsigned u32x4 __attribute__((ext_vector_type(4)));

// ---------------- Threefry-2x32, 20 rounds (bit-exact JAX) ----------------
__device__ __forceinline__ void tf2x32(unsigned k0, unsigned k1,
                                       unsigned x0, unsigned x1,
                                       unsigned& o0, unsigned& o1) {
  unsigned ks2 = k0 ^ k1 ^ 0x1BD11BDAu;
  x0 += k0; x1 += k1;
#define TFR(r) { x0 += x1; x1 = (x1 << (r)) | (x1 >> (32 - (r))); x1 ^= x0; }
  TFR(13) TFR(15) TFR(26) TFR(6)   x0 += k1;  x1 += ks2 + 1u;
  TFR(17) TFR(29) TFR(16) TFR(24)  x0 += ks2; x1 += k0 + 2u;
  TFR(13) TFR(15) TFR(26) TFR(6)   x0 += k0;  x1 += k1 + 3u;
  TFR(17) TFR(29) TFR(16) TFR(24)  x0 += k1;  x1 += ks2 + 4u;
  TFR(13) TFR(15) TFR(26) TFR(6)   x0 += ks2; x1 += k0 + 5u;
#undef TFR
  o0 = x0; o1 = x1;
}

__device__ __forceinline__ unsigned rbits(unsigned g0, unsigned g1,
                                          unsigned b, unsigned v) {
#if JAX_PARTITIONABLE
  unsigned y0, y1;
  tf2x32(g0, g1, 0u, b * (unsigned)V + v, y0, y1);
  return y0 ^ y1;
#else
  const unsigned N2 = (unsigned)(B/2) * (unsigned)V;
  unsigned ii = b * (unsigned)V + v;
  unsigned jj = (b < 256) ? ii : ii - N2;
  unsigned y0, y1;
  tf2x32(g0, g1, jj, N2 + jj, y0, y1);
  return (b < 256) ? y0 : y1;
#endif
}

__device__ __forceinline__ float u01_from_bits(unsigned bits) {
  return __uint_as_float(0x3f800000u | (bits >> 9)) - 1.0f;
}

__device__ __forceinline__ float gumbel_exact(unsigned bits) {
  float u = u01_from_bits(bits);
  if (u == 0.0f) u = 1.1754943508222875e-38f;
  float w = (float)(-log((double)u));
  return (float)(-log((double)w));
}

__device__ __forceinline__ float gumbel_fast(unsigned bits) {
  float u = u01_from_bits(bits);
  if (u == 0.0f) u = 1.1754943508222875e-38f;
  float w = -__logf(u);
  return -__logf(w);
}

__device__ __forceinline__ unsigned short f2bf(float f) {
  unsigned u = __float_as_uint(f);
  unsigned r = (u + 0x7fffu + ((u >> 16) & 1u)) >> 16;   // RNE, no NaN inputs
  return (unsigned short)r;
}

// fragment-major offset (in elements) for MFMA A/B operand layout:
// element (row, k) lives at [row>>4][k>>5][ (row&15) + 16*((k>>3)&3) ][ k&7 ]
__device__ __forceinline__ size_t frag_off(int row, int k, int kTiles) {
  return ((size_t)((row >> 4) * kTiles + (k >> 5)) * 64
          + (row & 15) + 16 * ((k >> 3) & 3)) * 8 + (k & 7);
}

// ---------------- init: per-step keys ----------------
__global__ void k_init_rng(unsigned* __restrict__ kq, unsigned* __restrict__ ke) {
  int t = threadIdx.x;  // 256 threads, 1 block
  unsigned h0, h1, e0, e1, g0, g1;
#if JAX_PARTITIONABLE
  tf2x32(0u, 42u, 0u, (unsigned)t, h0, h1);
  tf2x32(h0, h1, 0u, 0u, e0, e1);
  tf2x32(h0, h1, 0u, 1u, g0, g1);
#else
  unsigned a0, a1, b0, b1;
  if (t < 128) {
    tf2x32(0u, 42u, (unsigned)(2*t),   (unsigned)(256+2*t), a0, a1);
    tf2x32(0u, 42u, (unsigned)(2*t+1), (unsigned)(257+2*t), b0, b1);
    h0 = a0; h1 = b0;
  } else {
    int j = 2*t - 256;
    tf2x32(0u, 42u, (unsigned)j,     (unsigned)(256+j), a0, a1);
    tf2x32(0u, 42u, (unsigned)(j+1), (unsigned)(257+j), b0, b1);
    h0 = a1; h1 = b1;
  }
  unsigned p0, p1, q0, q1;
  tf2x32(h0, h1, 0u, 2u, p0, p1);
  tf2x32(h0, h1, 1u, 3u, q0, q1);
  e0 = p0; e1 = q0; g0 = p1; g1 = q1;
#endif
  ke[2*t] = e0; ke[2*t+1] = e1;
  kq[2*t] = g0; kq[2*t+1] = g1;
}

// ---------------- init: epsilon-greedy draw mask ----------------
__global__ void k_init_draws(const unsigned* __restrict__ ke,
                             unsigned char* __restrict__ draws) {
  int t = blockIdx.x;      // 0..255
  int b = threadIdx.x;     // 0..511
  unsigned k0 = ke[2*t], k1 = ke[2*t+1];
  unsigned bits, y0, y1;
#if JAX_PARTITIONABLE
  tf2x32(k0, k1, 0u, (unsigned)b, y0, y1);
  bits = y0 ^ y1;
#else
  if (b < 256) { tf2x32(k0, k1, (unsigned)b,       (unsigned)(256+b), y0, y1); bits = y0; }
  else         { tf2x32(k0, k1, (unsigned)(b-256), (unsigned)b,       y0, y1); bits = y1; }
#endif
  float u   = u01_from_bits(bits);
  float tf  = (float)t;
  float ex  = expf(__fmul_rn(-4.0f, tf) / 10000.0f);
  float eps = __fadd_rn(0.05f, __fmul_rn(0.95f, ex));
  draws[t*B + b] = (eps >= u) ? 1 : 0;
}

// ---------------- init: non-drawn slot assignment ----------------
__global__ void k_init_nd(const unsigned char* __restrict__ draws,
                          int* __restrict__ nd_slot) {
  int t = blockIdx.x;
  if (threadIdx.x != 0) return;
  int cnt = 0;
  for (int b = 0; b < B; b++) {
    if (!draws[t*B + b] && cnt < NDMAX) nd_slot[t*B + b] = cnt++;
    else nd_slot[t*B + b] = -1;
  }
}

// ---------------- init: precompute drawn-row samples (exact integer argmax) ----
__global__ __launch_bounds__(256) void k_pre_argmax(
    const unsigned* __restrict__ kq, const unsigned char* __restrict__ draws,
    int* __restrict__ pre) {
  const int job  = blockIdx.x * 4 + (threadIdx.x >> 6);   // [0, S*B)
  const int lane = threadIdx.x & 63;
  const int t = job >> 9, b = job & (B - 1);
  if (!draws[t*B + b]) { if (lane == 0) pre[job] = -1; return; }
  const unsigned g0 = kq[2*t], g1 = kq[2*t+1];
  unsigned best = 0u; int bv = V;
  for (int v = lane; v < V; v += 64) {
    unsigned bits = rbits(g0, g1, (unsigned)b, (unsigned)v) >> 9;
    if (bits > best || (bits == best && v < bv)) { best = bits; bv = v; }
  }
#pragma unroll
  for (int m = 1; m < 64; m <<= 1) {
    unsigned ob = __shfl_xor(best, m, 64);
    int      ov = __shfl_xor(bv,   m, 64);
    if (ob > best || (ob == best && ov < bv)) { best = ob; bv = ov; }
  }
  if (lane == 0) pre[job] = bv;
}

// ---------------- init: h=0, x=embedding[0] ----------------
__global__ void k_init_state(const float* __restrict__ emb,
                             float* __restrict__ x, float* __restrict__ h) {
  int b = blockIdx.x, tid = threadIdx.x;  // 256 threads
  x[b*E + tid] = emb[tid];
  h[b*H + tid] = 0.0f;
  h[b*H + 256 + tid] = 0.0f;
}

// ---------------- init: w_out -> bf16 in MFMA-fragment-major layout ----------
__global__ void k_cast_w(const float* __restrict__ w,
                         unsigned short* __restrict__ w_sw) {
  int g = blockIdx.x*256 + threadIdx.x;   // [0, V*H/8)
  int v  = g >> 6;
  int k0 = (g & 63) * 8;
  const float* src = w + (size_t)v*H + k0;
  union { unsigned short s[8]; u32x4 vv; } u;
#pragma unroll
  for (int e = 0; e < 8; e++) u.s[e] = f2bf(src[e]);
  *(u32x4*)&w_sw[frag_off(v, k0, H/32)] = u.vv;
}

// ---------------- GRU gate GEMMs (fp32; accumulation order FROZEN) ----------
__global__ __launch_bounds__(256) void k_gates(
    const float* __restrict__ x, const float* __restrict__ h,
    const float* __restrict__ w_ih, const float* __restrict__ w_hh,
    const float* __restrict__ b_ih, const float* __restrict__ b_hh,
    float* __restrict__ gi, float* __restrict__ gh) {
  const int z = blockIdx.z;
  const float* A    = z ? h    : x;
  const float* W    = z ? w_hh : w_ih;
  const float* bias = z ? b_hh : b_ih;
  float*       C    = z ? gh   : gi;
  const int K       = z ? H    : E;

  __shared__ __align__(16) float As[16][68];
  __shared__ __align__(16) float Ws[16][68];
  const int tid = threadIdx.x;
  const int tx = tid & 15, ty = tid >> 4;
  const int row0 = blockIdx.y * 64, col0 = blockIdx.x * 64;
  float acc[4][4] = {};
  for (int k0 = 0; k0 < K; k0 += 16) {
#pragma unroll
    for (int l = 0; l < 4; l++) {
      int idx = tid + l*256;
      int r = idx >> 4, kk = idx & 15;
      As[kk][r] = A[(row0 + r)*K + k0 + kk];
      Ws[kk][r] = W[(col0 + r)*K + k0 + kk];
    }
    __syncthreads();
#pragma unroll
    for (int kk = 0; kk < 16; kk++) {
      const float4 av = *(const float4*)&As[kk][ty*4];
      const float4 wv = *(const float4*)&Ws[kk][tx*4];
      const float a[4] = {av.x, av.y, av.z, av.w};
      const float w[4] = {wv.x, wv.y, wv.z, wv.w};
#pragma unroll
      for (int i = 0; i < 4; i++)
#pragma unroll
        for (int j = 0; j < 4; j++) acc[i][j] = fmaf(a[i], w[j], acc[i][j]);
    }
    __syncthreads();
  }
#pragma unroll
  for (int i = 0; i < 4; i++) {
    int r = row0 + ty*4 + i;
#pragma unroll
    for (int j = 0; j < 4; j++) {
      int c = col0 + tx*4 + j;
      C[r*G3 + c] = __fadd_rn(acc[i][j], bias[c]);
    }
  }
}

// ---------------- GRU update (8 elems/thread) + fragment-major bf16 h -------
__device__ __forceinline__ float sigm_acc(float v) {
  return (float)(1.0 / (1.0 + exp(-(double)v)));
}
__device__ __forceinline__ float tanh_acc(float v) {
  return (float)tanh((double)v);
}

__global__ void k_gru_update(const float* __restrict__ gi,
                             const float* __restrict__ gh,
                             float* __restrict__ h,
                             unsigned short* __restrict__ h_sw) {
  int g = blockIdx.x*256 + threadIdx.x;   // [0, B*H/8)
  int b  = g >> 6;
  int j0 = (g & 63) * 8;
  const float* gib = gi + (size_t)b*G3;
  const float* ghb = gh + (size_t)b*G3;
  float hn[8];
  union { unsigned short s[8]; u32x4 vv; } u;
#pragma unroll
  for (int e = 0; e < 8; e++) {
    int j = j0 + e;
    float r  = sigm_acc(__fadd_rn(gib[j],     ghb[j]));
    float zz = sigm_acc(__fadd_rn(gib[H+j],   ghb[H+j]));
    float nn = tanh_acc(__fadd_rn(gib[2*H+j], __fmul_rn(r, ghb[2*H+j])));
    float hv = h[(size_t)b*H + j];
    float t1 = __fmul_rn(__fsub_rn(1.0f, zz), nn);
    float t2 = __fmul_rn(zz, hv);
    hn[e] = __fadd_rn(t1, t2);
    u.s[e] = f2bf(hn[e]);
  }
#pragma unroll
  for (int e = 0; e < 8; e++) h[(size_t)b*H + j0 + e] = hn[e];
  *(u32x4*)&h_sw[frag_off(b, j0, H/32)] = u.vv;
}

// ---------------- bf16 MFMA logits GEMM, LDS-free fragment-direct ------------
// Tile 256(b) x 64(v), K=512. Grid (500, 2). Wave w owns rows
// [bblk*256 + w*64, +64) x all 64 cols. Frags loaded straight from the
// fragment-major h_sw / w_sw (coalesced 1KB per wave-load, no LDS, no barriers).
__global__ __launch_bounds__(256) void k_mfma_logits(
    const unsigned short* __restrict__ h_sw,
    const unsigned short* __restrict__ w_sw,
    const float* __restrict__ b_out,
    const unsigned* __restrict__ kq,
    const int* __restrict__ pre_t,       // pre + t*B
    const int* __restrict__ nd_slot_t,   // nd_slot + t*B
    float* __restrict__ pmax, float* __restrict__ psum,
    float* __restrict__ plog,
    float* __restrict__ nd_keys, float* __restrict__ nd_kmax, int t) {
  const int vblk = blockIdx.x;   // 0..499
  const int bblk = blockIdx.y;   // 0..1
  const int tid  = threadIdx.x;
  const int lane = tid & 63, w = tid >> 6;
  const int quad = lane >> 4, l15 = lane & 15;

  f32x4 acc[4][4] = {};

  // per-(tile,kt) stride in elements: one tile-row of 16 kTiles, each 512 elems
  const int mtBase = bblk*16 + w*4;   // h rowTile base
  const int ntBase = vblk*4;          // w rowTile base
  const unsigned short* hp = h_sw + (size_t)mtBase*16*512 + lane*8;
  const unsigned short* wp = w_sw + (size_t)ntBase*16*512 + lane*8;

#pragma unroll 2
  for (int kt = 0; kt < 16; kt++) {
    bf16x8 af[4], bfv[4];
#pragma unroll
    for (int mt = 0; mt < 4; mt++)
      af[mt] = __builtin_bit_cast(bf16x8,
          *(const u32x4*)(hp + (size_t)(mt*16 + kt)*512));
#pragma unroll
    for (int nt = 0; nt < 4; nt++)
      bfv[nt] = __builtin_bit_cast(bf16x8,
          *(const u32x4*)(wp + (size_t)(nt*16 + kt)*512));
#pragma unroll
    for (int mt = 0; mt < 4; mt++)
#pragma unroll
      for (int nt = 0; nt < 4; nt++)
        acc[mt][nt] = __builtin_amdgcn_mfma_f32_16x16x32_bf16(
            af[mt], bfv[nt], acc[mt][nt], 0, 0, 0);
  }

  // epilogue: lane holds D[b = bW + mt*16 + quad*4 + r][v = vW + nt*16 + l15]
  const int bW = bblk*256 + w*64;
  const int vW = vblk*64;
  const unsigned g0 = kq[2*t], g1 = kq[2*t+1];
  float bias[4];
#pragma unroll
  for (int nt = 0; nt < 4; nt++) bias[nt] = b_out[vW + nt*16 + l15];

#pragma unroll
  for (int mt = 0; mt < 4; mt++) {
#pragma unroll
    for (int r = 0; r < 4; r++) {
      const int b = bW + mt*16 + quad*4 + r;
      float lg[4];
#pragma unroll
      for (int nt = 0; nt < 4; nt++) lg[nt] = acc[mt][nt][r] + bias[nt];
      float lmax = fmaxf(fmaxf(lg[0], lg[1]), fmaxf(lg[2], lg[3]));
#pragma unroll
      for (int m = 1; m < 16; m <<= 1) lmax = fmaxf(lmax, __shfl_xor(lmax, m, 64));
      float ls = 0.0f;
#pragma unroll
      for (int nt = 0; nt < 4; nt++) ls += __expf(lg[nt] - lmax);
#pragma unroll
      for (int m = 1; m < 16; m <<= 1) ls += __shfl_xor(ls, m, 64);
      if (l15 == 0) { pmax[b*NCH + vblk] = lmax; psum[b*NCH + vblk] = ls; }
      const int pr = pre_t[b];
      if (pr >= 0) {
        int rel = pr - vW;
        if (rel >= 0 && rel < 64 && (rel & 15) == l15) plog[b] = lg[rel >> 4];
      } else {
        const int slot = nd_slot_t[b];
        if (slot >= 0) {
          float key[4];
#pragma unroll
          for (int nt = 0; nt < 4; nt++)
            key[nt] = lg[nt] + gumbel_fast(
                rbits(g0, g1, (unsigned)b, (unsigned)(vW + nt*16 + l15)));
          float* dst = nd_keys + (size_t)slot*V + vW + l15;
#pragma unroll
          for (int nt = 0; nt < 4; nt++) dst[nt*16] = key[nt];
          float kmx = fmaxf(fmaxf(key[0], key[1]), fmaxf(key[2], key[3]));
#pragma unroll
          for (int m = 1; m < 16; m <<= 1) kmx = fmaxf(kmx, __shfl_xor(kmx, m, 64));
          if (l15 == 0) nd_kmax[slot*NCH + vblk] = kmx;
        }
      }
    }
  }
}

// ---------------- fused finish: lse + (nd candidate pick) + outputs ---------
__global__ __launch_bounds__(256) void k_finish(
    const float* __restrict__ pmax, const float* __restrict__ psum,
    const float* __restrict__ plog,
    const int* __restrict__ pre_t, const int* __restrict__ nd_slot_t,
    const float* __restrict__ nd_keys, const float* __restrict__ nd_kmax,
    const unsigned* __restrict__ kq,
    const float* __restrict__ h, const float* __restrict__ w_out,
    const float* __restrict__ b_out,
    const float* __restrict__ emb, float* __restrict__ x,
    float* __restrict__ out_samples, float* __restrict__ out_lps, int t) {
  const int b = blockIdx.x;
  const int tid = threadIdx.x;
  __shared__ float sA[256];
  __shared__ int   cand[160];
  __shared__ float cand_key[160], cand_lg[160];
  __shared__ int   ccnt;
  __shared__ int   s_samp;
  __shared__ float s_blog;

  // ---- softmax lse over 500 chunk partials ----
  float m = -INFINITY;
  for (int c = tid; c < NCH; c += 256) m = fmaxf(m, pmax[b*NCH + c]);
  sA[tid] = m; __syncthreads();
  for (int s = 128; s > 0; s >>= 1) {
    if (tid < s) sA[tid] = fmaxf(sA[tid], sA[tid+s]);
    __syncthreads();
  }
  const float M = sA[0];
  __syncthreads();
  float sum = 0.0f;
  for (int c = tid; c < NCH; c += 256)
    sum += psum[b*NCH + c] * expf(pmax[b*NCH + c] - M);
  sA[tid] = sum; __syncthreads();
  for (int s = 128; s > 0; s >>= 1) {
    if (tid < s) sA[tid] += sA[tid+s];
    __syncthreads();
  }
  const float SUM = sA[0];
  __syncthreads();

  // ---- pick the sample ----
  const int pr = pre_t[b];             // block-uniform
  if (pr >= 0) {
    if (tid == 0) { s_samp = pr; s_blog = plog[b]; }
  } else {
    const int slot = nd_slot_t[b];
    if (slot < 0) {                    // statistically impossible overflow guard
      if (tid == 0) { s_samp = 0; s_blog = plog[b]; }
    } else {
      const unsigned g0 = kq[2*t], g1 = kq[2*t+1];
      if (tid == 0) ccnt = 0;
      float km = -INFINITY;
      for (int c = tid; c < NCH; c += 256) km = fmaxf(km, nd_kmax[slot*NCH + c]);
      sA[tid] = km; __syncthreads();
      for (int s = 128; s > 0; s >>= 1) {
        if (tid < s) sA[tid] = fmaxf(sA[tid], sA[tid+s]);
        __syncthreads();
      }
      const float thr = sA[0] - 0.0859375f;  // >= 2*(bf16 err + fastlog err)
      __syncthreads();
      const float* keys = nd_keys + (size_t)slot*V;
      for (int c = tid; c < NCH; c += 256) {
        if (nd_kmax[slot*NCH + c] >= thr) {
          for (int j = 0; j < VBLK; j++) {
            float k = keys[c*VBLK + j];
            if (k >= thr) {
              int p = atomicAdd(&ccnt, 1);
              if (p < 160) cand[p] = c*VBLK + j;
            }
          }
        }
      }
      __syncthreads();
      const int nc = min(ccnt, 160);
      const int wid = tid >> 6, lane = tid & 63;
      for (int c = wid; c < nc; c += 4) {
        const int v = cand[c];
        const float* wr = w_out + (size_t)v*H;
        const float* hr = h + (size_t)b*H;
        float s = 0.0f;
#pragma unroll
        for (int i = 0; i < 8; i++) s = fmaf(hr[lane + 64*i], wr[lane + 64*i], s);
#pragma unroll
        for (int mm = 1; mm < 64; mm <<= 1) s += __shfl_xor(s, mm, 64);
        if (lane == 0) {
          float logit = __fadd_rn(s, b_out[v]);
          float key   = __fadd_rn(logit,
                          gumbel_exact(rbits(g0, g1, (unsigned)b, (unsigned)v)));
          cand_key[c] = key; cand_lg[c] = logit;
        }
      }
      __syncthreads();
      if (tid == 0) {
        float bk = -INFINITY; int bv = V; float bl = 0.0f;
        for (int c = 0; c < nc; c++) {
          float k = cand_key[c]; int v = cand[c];
          if (k > bk || (k == bk && v < bv)) { bk = k; bv = v; bl = cand_lg[c]; }
        }
        s_samp = bv; s_blog = bl;
      }
    }
  }
  __syncthreads();
  const int sampled = s_samp;
  if (tid == 0) {
    float lse = (float)log((double)SUM);
    float lp  = __fsub_rn(__fsub_rn(s_blog, M), lse);
    out_samples[b*S + t] = (float)sampled;
    out_lps[b*S + t]     = lp;
  }
  x[b*E + tid] = emb[sampled*E + tid];
}

} // namespace

extern "C" void kernel_launch(void* const* d_in, const int* in_sizes, int n_in,
                              void* d_out, int out_size, void* d_ws, size_t ws_size,
                              hipStream_t stream) {
  (void)in_sizes; (void)n_in; (void)out_size;
  const float* emb   = (const float*)d_in[0];
  const float* w_ih  = (const float*)d_in[1];
  const float* w_hh  = (const float*)d_in[2];
  const float* b_ih  = (const float*)d_in[3];
  const float* b_hh  = (const float*)d_in[4];
  const float* w_out = (const float*)d_in[5];
  const float* b_out = (const float*)d_in[6];
  float* out = (float*)d_out;

  char* wsb = (char*)d_ws;
  size_t off = 0;
  auto alloc = [&](size_t nbytes) {
    char* p = wsb + off;
    off += (nbytes + 255) & ~size_t(255);
    return p;
  };
  float* h     = (float*)alloc((size_t)B*H*4);
  float* x     = (float*)alloc((size_t)B*E*4);
  float* gi    = (float*)alloc((size_t)B*G3*4);
  float* gh    = (float*)alloc((size_t)B*G3*4);
  unsigned short* h_sw = (unsigned short*)alloc((size_t)B*H*2);
  unsigned short* w_sw = (unsigned short*)alloc((size_t)V*H*2);
  float* pmax  = (float*)alloc((size_t)B*NCH*4);
  float* psum  = (float*)alloc((size_t)B*NCH*4);
  float* plog  = (float*)alloc((size_t)B*4);
  unsigned* kq = (unsigned*)alloc((size_t)S*2*4);
  unsigned* ke = (unsigned*)alloc((size_t)S*2*4);
  unsigned char* draws = (unsigned char*)alloc((size_t)S*B);
  int* pre     = (int*)alloc((size_t)S*B*4);
  int* nd_slot = (int*)alloc((size_t)S*B*4);
  float* nd_keys = (float*)alloc((size_t)NDMAX*V*4);
  float* nd_kmax = (float*)alloc((size_t)NDMAX*NCH*4);
  if (off > ws_size) {
    fprintf(stderr, "kernel_launch: workspace too small (need %zu, have %zu)\n",
            off, ws_size);
    return;
  }

  k_init_rng<<<1, S, 0, stream>>>(kq, ke);
  k_init_draws<<<S, B, 0, stream>>>(ke, draws);
  k_init_nd<<<S, 64, 0, stream>>>(draws, nd_slot);
  k_pre_argmax<<<(S*B)/4, 256, 0, stream>>>(kq, draws, pre);
  k_init_state<<<B, 256, 0, stream>>>(emb, x, h);
  k_cast_w<<<(V*H/8)/256, 256, 0, stream>>>(w_out, w_sw);

  for (int t = 0; t < S; t++) {
    k_gates<<<dim3(G3/64, B/64, 2), 256, 0, stream>>>(x, h, w_ih, w_hh,
                                                      b_ih, b_hh, gi, gh);
    k_gru_update<<<(B*H/8)/256, 256, 0, stream>>>(gi, gh, h, h_sw);
    k_mfma_logits<<<dim3(V/VBLK, B/BBLK), 256, 0, stream>>>(
        h_sw, w_sw, b_out, kq, pre + t*B, nd_slot + t*B,
        pmax, psum, plog, nd_keys, nd_kmax, t);
    k_finish<<<B, 256, 0, stream>>>(pmax, psum, plog, pre + t*B, nd_slot + t*B,
                                    nd_keys, nd_kmax, kq, h, w_out, b_out,
                                    emb, x, out, out + (size_t)B*S, t);
  }
}

// Round 7
// 35874.115 us; speedup vs baseline: 1.1691x; 1.1691x over previous
//
#include <hip/hip_runtime.h>
#include <math.h>
#include <stdio.h>

#ifndef JAX_PARTITIONABLE
#define JAX_PARTITIONABLE 1
#endif

namespace {

constexpr int B  = 512;
constexpr int S  = 256;
constexpr int E  = 256;
constexpr int H  = 512;
constexpr int V  = 32000;
constexpr int G3 = 3 * H;      // 1536
constexpr int VBLK = 64;       // v-tile (also the softmax chunk width)
constexpr int BBLK = 256;      // b-tile
constexpr int NCH  = V / VBLK; // 500 chunks
constexpr int NDMAX = 96;      // max non-drawn rows per step (mean<=47)

typedef __bf16 bf16x8 __attribute__((ext_vector_type(8)));
typedef float  f32x4  __attribute__((ext_vector_type(4)));
typedef unsigned u32x4 __attribute__((ext_vector_type(4)));

// ---------------- Threefry-2x32, 20 rounds (bit-exact JAX) ----------------
__device__ __forceinline__ void tf2x32(unsigned k0, unsigned k1,
                                       unsigned x0, unsigned x1,
                                       unsigned& o0, unsigned& o1) {
  unsigned ks2 = k0 ^ k1 ^ 0x1BD11BDAu;
  x0 += k0; x1 += k1;
#define TFR(r) { x0 += x1; x1 = (x1 << (r)) | (x1 >> (32 - (r))); x1 ^= x0; }
  TFR(13) TFR(15) TFR(26) TFR(6)   x0 += k1;  x1 += ks2 + 1u;
  TFR(17) TFR(29) TFR(16) TFR(24)  x0 += ks2; x1 += k0 + 2u;
  TFR(13) TFR(15) TFR(26) TFR(6)   x0 += k0;  x1 += k1 + 3u;
  TFR(17) TFR(29) TFR(16) TFR(24)  x0 += k1;  x1 += ks2 + 4u;
  TFR(13) TFR(15) TFR(26) TFR(6)   x0 += ks2; x1 += k0 + 5u;
#undef TFR
  o0 = x0; o1 = x1;
}

__device__ __forceinline__ unsigned rbits(unsigned g0, unsigned g1,
                                          unsigned b, unsigned v) {
#if JAX_PARTITIONABLE
  unsigned y0, y1;
  tf2x32(g0, g1, 0u, b * (unsigned)V + v, y0, y1);
  return y0 ^ y1;
#else
  const unsigned N2 = (unsigned)(B/2) * (unsigned)V;
  unsigned ii = b * (unsigned)V + v;
  unsigned jj = (b < 256) ? ii : ii - N2;
  unsigned y0, y1;
  tf2x32(g0, g1, jj, N2 + jj, y0, y1);
  return (b < 256) ? y0 : y1;
#endif
}

__device__ __forceinline__ float u01_from_bits(unsigned bits) {
  return __uint_as_float(0x3f800000u | (bits >> 9)) - 1.0f;
}

__device__ __forceinline__ float gumbel_exact(unsigned bits) {
  float u = u01_from_bits(bits);
  if (u == 0.0f) u = 1.1754943508222875e-38f;
  float w = (float)(-log((double)u));
  return (float)(-log((double)w));
}

__device__ __forceinline__ float gumbel_fast(unsigned bits) {
  float u = u01_from_bits(bits);
  if (u == 0.0f) u = 1.1754943508222875e-38f;
  float w = -__logf(u);
  return -__logf(w);
}

__device__ __forceinline__ unsigned short f2bf(float f) {
  unsigned u = __float_as_uint(f);
  unsigned r = (u + 0x7fffu + ((u >> 16) & 1u)) >> 16;   // RNE, no NaN inputs
  return (unsigned short)r;
}

// async global->LDS, 16 bytes per lane; our LDS layout is exactly
// wave-uniform base + lane*16, as required.
__device__ __forceinline__ void glds16(const unsigned short* g,
                                       unsigned short* l) {
  __builtin_amdgcn_global_load_lds(
      (const __attribute__((address_space(1))) unsigned int*)g,
      (__attribute__((address_space(3))) unsigned int*)l, 16, 0, 0);
}

// fragment-major offset (in elements) for MFMA A/B operand layout:
// element (row, k) lives at [row>>4][k>>5][ (row&15) + 16*((k>>3)&3) ][ k&7 ]
__device__ __forceinline__ size_t frag_off(int row, int k, int kTiles) {
  return ((size_t)((row >> 4) * kTiles + (k >> 5)) * 64
          + (row & 15) + 16 * ((k >> 3) & 3)) * 8 + (k & 7);
}

// ---------------- init: per-step keys ----------------
__global__ void k_init_rng(unsigned* __restrict__ kq, unsigned* __restrict__ ke) {
  int t = threadIdx.x;  // 256 threads, 1 block
  unsigned h0, h1, e0, e1, g0, g1;
#if JAX_PARTITIONABLE
  tf2x32(0u, 42u, 0u, (unsigned)t, h0, h1);
  tf2x32(h0, h1, 0u, 0u, e0, e1);
  tf2x32(h0, h1, 0u, 1u, g0, g1);
#else
  unsigned a0, a1, b0, b1;
  if (t < 128) {
    tf2x32(0u, 42u, (unsigned)(2*t),   (unsigned)(256+2*t), a0, a1);
    tf2x32(0u, 42u, (unsigned)(2*t+1), (unsigned)(257+2*t), b0, b1);
    h0 = a0; h1 = b0;
  } else {
    int j = 2*t - 256;
    tf2x32(0u, 42u, (unsigned)j,     (unsigned)(256+j), a0, a1);
    tf2x32(0u, 42u, (unsigned)(j+1), (unsigned)(257+j), b0, b1);
    h0 = a1; h1 = b1;
  }
  unsigned p0, p1, q0, q1;
  tf2x32(h0, h1, 0u, 2u, p0, p1);
  tf2x32(h0, h1, 1u, 3u, q0, q1);
  e0 = p0; e1 = q0; g0 = p1; g1 = q1;
#endif
  ke[2*t] = e0; ke[2*t+1] = e1;
  kq[2*t] = g0; kq[2*t+1] = g1;
}

// ---------------- init: epsilon-greedy draw mask ----------------
__global__ void k_init_draws(const unsigned* __restrict__ ke,
                             unsigned char* __restrict__ draws) {
  int t = blockIdx.x;      // 0..255
  int b = threadIdx.x;     // 0..511
  unsigned k0 = ke[2*t], k1 = ke[2*t+1];
  unsigned bits, y0, y1;
#if JAX_PARTITIONABLE
  tf2x32(k0, k1, 0u, (unsigned)b, y0, y1);
  bits = y0 ^ y1;
#else
  if (b < 256) { tf2x32(k0, k1, (unsigned)b,       (unsigned)(256+b), y0, y1); bits = y0; }
  else         { tf2x32(k0, k1, (unsigned)(b-256), (unsigned)b,       y0, y1); bits = y1; }
#endif
  float u   = u01_from_bits(bits);
  float tf  = (float)t;
  float ex  = expf(__fmul_rn(-4.0f, tf) / 10000.0f);
  float eps = __fadd_rn(0.05f, __fmul_rn(0.95f, ex));
  draws[t*B + b] = (eps >= u) ? 1 : 0;
}

// ---------------- init: non-drawn slot assignment ----------------
__global__ void k_init_nd(const unsigned char* __restrict__ draws,
                          int* __restrict__ nd_slot) {
  int t = blockIdx.x;
  if (threadIdx.x != 0) return;
  int cnt = 0;
  for (int b = 0; b < B; b++) {
    if (!draws[t*B + b] && cnt < NDMAX) nd_slot[t*B + b] = cnt++;
    else nd_slot[t*B + b] = -1;
  }
}

// ---------------- init: precompute drawn-row samples (exact integer argmax) ----
__global__ __launch_bounds__(256) void k_pre_argmax(
    const unsigned* __restrict__ kq, const unsigned char* __restrict__ draws,
    int* __restrict__ pre) {
  const int job  = blockIdx.x * 4 + (threadIdx.x >> 6);   // [0, S*B)
  const int lane = threadIdx.x & 63;
  const int t = job >> 9, b = job & (B - 1);
  if (!draws[t*B + b]) { if (lane == 0) pre[job] = -1; return; }
  const unsigned g0 = kq[2*t], g1 = kq[2*t+1];
  unsigned best = 0u; int bv = V;
  for (int v = lane; v < V; v += 64) {
    unsigned bits = rbits(g0, g1, (unsigned)b, (unsigned)v) >> 9;
    if (bits > best || (bits == best && v < bv)) { best = bits; bv = v; }
  }
#pragma unroll
  for (int m = 1; m < 64; m <<= 1) {
    unsigned ob = __shfl_xor(best, m, 64);
    int      ov = __shfl_xor(bv,   m, 64);
    if (ob > best || (ob == best && ov < bv)) { best = ob; bv = ov; }
  }
  if (lane == 0) pre[job] = bv;
}

// ---------------- init: h=0, x=embedding[0] ----------------
__global__ void k_init_state(const float* __restrict__ emb,
                             float* __restrict__ x, float* __restrict__ h) {
  int b = blockIdx.x, tid = threadIdx.x;  // 256 threads
  x[b*E + tid] = emb[tid];
  h[b*H + tid] = 0.0f;
  h[b*H + 256 + tid] = 0.0f;
}

// ---------------- init: w_out -> bf16 in MFMA-fragment-major layout ----------
__global__ void k_cast_w(const float* __restrict__ w,
                         unsigned short* __restrict__ w_sw) {
  int g = blockIdx.x*256 + threadIdx.x;   // [0, V*H/8)
  int v  = g >> 6;
  int k0 = (g & 63) * 8;
  const float* src = w + (size_t)v*H + k0;
  union { unsigned short s[8]; u32x4 vv; } u;
#pragma unroll
  for (int e = 0; e < 8; e++) u.s[e] = f2bf(src[e]);
  *(u32x4*)&w_sw[frag_off(v, k0, H/32)] = u.vv;
}

// ---------------- GRU gate GEMMs (fp32; accumulation order FROZEN) ----------
__global__ __launch_bounds__(256) void k_gates(
    const float* __restrict__ x, const float* __restrict__ h,
    const float* __restrict__ w_ih, const float* __restrict__ w_hh,
    const float* __restrict__ b_ih, const float* __restrict__ b_hh,
    float* __restrict__ gi, float* __restrict__ gh) {
  const int z = blockIdx.z;
  const float* A    = z ? h    : x;
  const float* W    = z ? w_hh : w_ih;
  const float* bias = z ? b_hh : b_ih;
  float*       C    = z ? gh   : gi;
  const int K       = z ? H    : E;

  __shared__ __align__(16) float As[16][68];
  __shared__ __align__(16) float Ws[16][68];
  const int tid = threadIdx.x;
  const int tx = tid & 15, ty = tid >> 4;
  const int row0 = blockIdx.y * 64, col0 = blockIdx.x * 64;
  float acc[4][4] = {};
  for (int k0 = 0; k0 < K; k0 += 16) {
#pragma unroll
    for (int l = 0; l < 4; l++) {
      int idx = tid + l*256;
      int r = idx >> 4, kk = idx & 15;
      As[kk][r] = A[(row0 + r)*K + k0 + kk];
      Ws[kk][r] = W[(col0 + r)*K + k0 + kk];
    }
    __syncthreads();
#pragma unroll
    for (int kk = 0; kk < 16; kk++) {
      const float4 av = *(const float4*)&As[kk][ty*4];
      const float4 wv = *(const float4*)&Ws[kk][tx*4];
      const float a[4] = {av.x, av.y, av.z, av.w};
      const float w[4] = {wv.x, wv.y, wv.z, wv.w};
#pragma unroll
      for (int i = 0; i < 4; i++)
#pragma unroll
        for (int j = 0; j < 4; j++) acc[i][j] = fmaf(a[i], w[j], acc[i][j]);
    }
    __syncthreads();
  }
#pragma unroll
  for (int i = 0; i < 4; i++) {
    int r = row0 + ty*4 + i;
#pragma unroll
    for (int j = 0; j < 4; j++) {
      int c = col0 + tx*4 + j;
      C[r*G3 + c] = __fadd_rn(acc[i][j], bias[c]);
    }
  }
}

// ---------------- GRU update (8 elems/thread) + fragment-major bf16 h -------
__device__ __forceinline__ float sigm_acc(float v) {
  return (float)(1.0 / (1.0 + exp(-(double)v)));
}
__device__ __forceinline__ float tanh_acc(float v) {
  return (float)tanh((double)v);
}

__global__ void k_gru_update(const float* __restrict__ gi,
                             const float* __restrict__ gh,
                             float* __restrict__ h,
                             unsigned short* __restrict__ h_sw) {
  int g = blockIdx.x*256 + threadIdx.x;   // [0, B*H/8)
  int b  = g >> 6;
  int j0 = (g & 63) * 8;
  const float* gib = gi + (size_t)b*G3;
  const float* ghb = gh + (size_t)b*G3;
  float hn[8];
  union { unsigned short s[8]; u32x4 vv; } u;
#pragma unroll
  for (int e = 0; e < 8; e++) {
    int j = j0 + e;
    float r  = sigm_acc(__fadd_rn(gib[j],     ghb[j]));
    float zz = sigm_acc(__fadd_rn(gib[H+j],   ghb[H+j]));
    float nn = tanh_acc(__fadd_rn(gib[2*H+j], __fmul_rn(r, ghb[2*H+j])));
    float hv = h[(size_t)b*H + j];
    float t1 = __fmul_rn(__fsub_rn(1.0f, zz), nn);
    float t2 = __fmul_rn(zz, hv);
    hn[e] = __fadd_rn(t1, t2);
    u.s[e] = f2bf(hn[e]);
  }
#pragma unroll
  for (int e = 0; e < 8; e++) h[(size_t)b*H + j0 + e] = hn[e];
  *(u32x4*)&h_sw[frag_off(b, j0, H/32)] = u.vv;
}

// ---------------- bf16 MFMA logits GEMM: hybrid staging ---------------------
// Tile 256(b) x 64(v), K=512, grid (500,2). A(h): direct fragment-major
// global loads (L2-resident, zero intra-block reuse). B(w): glds16 DMA into
// double-buffered LDS (4x wave reuse), one barrier/iter, DMA overlaps MFMA.
__global__ __launch_bounds__(256) void k_mfma_logits(
    const unsigned short* __restrict__ h_sw,
    const unsigned short* __restrict__ w_sw,
    const float* __restrict__ b_out,
    const unsigned* __restrict__ kq,
    const int* __restrict__ pre_t,       // pre + t*B
    const int* __restrict__ nd_slot_t,   // nd_slot + t*B
    float* __restrict__ pmax, float* __restrict__ psum,
    float* __restrict__ plog,
    float* __restrict__ nd_keys, float* __restrict__ nd_kmax, int t) {
  const int vblk = blockIdx.x;   // 0..499
  const int bblk = blockIdx.y;   // 0..1
  const int tid  = threadIdx.x;
  const int lane = tid & 63, w = tid >> 6;
  const int quad = lane >> 4, l15 = lane & 15;

  __shared__ __align__(16) unsigned short wt[2][4*512];  // 2 x 4 KB

  f32x4 acc[4][4] = {};

  const int mtBase = bblk*16 + w*4;   // h rowTile base for this wave
  const int ntBase = vblk*4;          // w rowTile base
  const unsigned short* hp = h_sw + (size_t)mtBase*16*512 + lane*8;
  // wave w stages rowTile ntBase+w (wave-uniform base + lane*16B)
  const unsigned short* wstage = w_sw + (size_t)(ntBase + w)*16*512 + lane*8;
  unsigned short* ldst = &wt[0][0] + tid*8;

  // prologue: stage kt=0, prefetch A-frags for kt=0
  glds16(wstage, ldst);
  bf16x8 afc[4];
#pragma unroll
  for (int mt = 0; mt < 4; mt++)
    afc[mt] = __builtin_bit_cast(bf16x8, *(const u32x4*)(hp + (size_t)(mt*16)*512));

#pragma unroll 1
  for (int kt = 0; kt < 15; kt++) {
    const int p = kt & 1;
    __syncthreads();                    // buf[p] DMA drained; buf[p^1] reads done
    glds16(wstage + (size_t)(kt + 1)*512, ldst + (p ^ 1)*2048);
    bf16x8 afn[4];
#pragma unroll
    for (int mt = 0; mt < 4; mt++)
      afn[mt] = __builtin_bit_cast(bf16x8,
          *(const u32x4*)(hp + (size_t)(mt*16 + kt + 1)*512));
    bf16x8 bfv[4];
#pragma unroll
    for (int nt = 0; nt < 4; nt++)
      bfv[nt] = __builtin_bit_cast(bf16x8,
          *(const u32x4*)&wt[p][nt*512 + lane*8]);
#pragma unroll
    for (int mt = 0; mt < 4; mt++)
#pragma unroll
      for (int nt = 0; nt < 4; nt++)
        acc[mt][nt] = __builtin_amdgcn_mfma_f32_16x16x32_bf16(
            afc[mt], bfv[nt], acc[mt][nt], 0, 0, 0);
#pragma unroll
    for (int mt = 0; mt < 4; mt++) afc[mt] = afn[mt];
  }
  {  // kt = 15, p = 1
    __syncthreads();
    bf16x8 bfv[4];
#pragma unroll
    for (int nt = 0; nt < 4; nt++)
      bfv[nt] = __builtin_bit_cast(bf16x8,
          *(const u32x4*)&wt[1][nt*512 + lane*8]);
#pragma unroll
    for (int mt = 0; mt < 4; mt++)
#pragma unroll
      for (int nt = 0; nt < 4; nt++)
        acc[mt][nt] = __builtin_amdgcn_mfma_f32_16x16x32_bf16(
            afc[mt], bfv[nt], acc[mt][nt], 0, 0, 0);
  }

  // epilogue: lane holds D[b = bW + mt*16 + quad*4 + r][v = vW + nt*16 + l15]
  const int bW = bblk*256 + w*64;
  const int vW = vblk*64;
  const unsigned g0 = kq[2*t], g1 = kq[2*t+1];
  float bias[4];
#pragma unroll
  for (int nt = 0; nt < 4; nt++) bias[nt] = b_out[vW + nt*16 + l15];

#pragma unroll
  for (int mt = 0; mt < 4; mt++) {
#pragma unroll
    for (int r = 0; r < 4; r++) {
      const int b = bW + mt*16 + quad*4 + r;
      float lg[4];
#pragma unroll
      for (int nt = 0; nt < 4; nt++) lg[nt] = acc[mt][nt][r] + bias[nt];
      float lmax = fmaxf(fmaxf(lg[0], lg[1]), fmaxf(lg[2], lg[3]));
#pragma unroll
      for (int m = 1; m < 16; m <<= 1) lmax = fmaxf(lmax, __shfl_xor(lmax, m, 64));
      float ls = 0.0f;
#pragma unroll
      for (int nt = 0; nt < 4; nt++) ls += __expf(lg[nt] - lmax);
#pragma unroll
      for (int m = 1; m < 16; m <<= 1) ls += __shfl_xor(ls, m, 64);
      if (l15 == 0) { pmax[b*NCH + vblk] = lmax; psum[b*NCH + vblk] = ls; }
      const int pr = pre_t[b];
      if (pr >= 0) {
        int rel = pr - vW;
        if (rel >= 0 && rel < 64 && (rel & 15) == l15) plog[b] = lg[rel >> 4];
      } else {
        const int slot = nd_slot_t[b];
        if (slot >= 0) {
          float key[4];
#pragma unroll
          for (int nt = 0; nt < 4; nt++)
            key[nt] = lg[nt] + gumbel_fast(
                rbits(g0, g1, (unsigned)b, (unsigned)(vW + nt*16 + l15)));
          float* dst = nd_keys + (size_t)slot*V + vW + l15;
#pragma unroll
          for (int nt = 0; nt < 4; nt++) dst[nt*16] = key[nt];
          float kmx = fmaxf(fmaxf(key[0], key[1]), fmaxf(key[2], key[3]));
#pragma unroll
          for (int m = 1; m < 16; m <<= 1) kmx = fmaxf(kmx, __shfl_xor(kmx, m, 64));
          if (l15 == 0) nd_kmax[slot*NCH + vblk] = kmx;
        }
      }
    }
  }
}

// ---------------- fused finish: lse + (nd candidate pick) + outputs ---------
__global__ __launch_bounds__(256) void k_finish(
    const float* __restrict__ pmax, const float* __restrict__ psum,
    const float* __restrict__ plog,
    const int* __restrict__ pre_t, const int* __restrict__ nd_slot_t,
    const float* __restrict__ nd_keys, const float* __restrict__ nd_kmax,
    const unsigned* __restrict__ kq,
    const float* __restrict__ h, const float* __restrict__ w_out,
    const float* __restrict__ b_out,
    const float* __restrict__ emb, float* __restrict__ x,
    float* __restrict__ out_samples, float* __restrict__ out_lps, int t) {
  const int b = blockIdx.x;
  const int tid = threadIdx.x;
  __shared__ float sA[256];
  __shared__ int   cand[160];
  __shared__ float cand_key[160], cand_lg[160];
  __shared__ int   ccnt;
  __shared__ int   s_samp;
  __shared__ float s_blog;

  // ---- softmax lse over 500 chunk partials ----
  float m = -INFINITY;
  for (int c = tid; c < NCH; c += 256) m = fmaxf(m, pmax[b*NCH + c]);
  sA[tid] = m; __syncthreads();
  for (int s = 128; s > 0; s >>= 1) {
    if (tid < s) sA[tid] = fmaxf(sA[tid], sA[tid+s]);
    __syncthreads();
  }
  const float M = sA[0];
  __syncthreads();
  float sum = 0.0f;
  for (int c = tid; c < NCH; c += 256)
    sum += psum[b*NCH + c] * expf(pmax[b*NCH + c] - M);
  sA[tid] = sum; __syncthreads();
  for (int s = 128; s > 0; s >>= 1) {
    if (tid < s) sA[tid] += sA[tid+s];
    __syncthreads();
  }
  const float SUM = sA[0];
  __syncthreads();

  // ---- pick the sample ----
  const int pr = pre_t[b];             // block-uniform
  if (pr >= 0) {
    if (tid == 0) { s_samp = pr; s_blog = plog[b]; }
  } else {
    const int slot = nd_slot_t[b];
    if (slot < 0) {                    // statistically impossible overflow guard
      if (tid == 0) { s_samp = 0; s_blog = plog[b]; }
    } else {
      const unsigned g0 = kq[2*t], g1 = kq[2*t+1];
      if (tid == 0) ccnt = 0;
      float km = -INFINITY;
      for (int c = tid; c < NCH; c += 256) km = fmaxf(km, nd_kmax[slot*NCH + c]);
      sA[tid] = km; __syncthreads();
      for (int s = 128; s > 0; s >>= 1) {
        if (tid < s) sA[tid] = fmaxf(sA[tid], sA[tid+s]);
        __syncthreads();
      }
      const float thr = sA[0] - 0.0859375f;  // >= 2*(bf16 err + fastlog err)
      __syncthreads();
      const float* keys = nd_keys + (size_t)slot*V;
      for (int c = tid; c < NCH; c += 256) {
        if (nd_kmax[slot*NCH + c] >= thr) {
          for (int j = 0; j < VBLK; j++) {
            float k = keys[c*VBLK + j];
            if (k >= thr) {
              int p = atomicAdd(&ccnt, 1);
              if (p < 160) cand[p] = c*VBLK + j;
            }
          }
        }
      }
      __syncthreads();
      const int nc = min(ccnt, 160);
      const int wid = tid >> 6, lane = tid & 63;
      for (int c = wid; c < nc; c += 4) {
        const int v = cand[c];
        const float* wr = w_out + (size_t)v*H;
        const float* hr = h + (size_t)b*H;
        float s = 0.0f;
#pragma unroll
        for (int i = 0; i < 8; i++) s = fmaf(hr[lane + 64*i], wr[lane + 64*i], s);
#pragma unroll
        for (int mm = 1; mm < 64; mm <<= 1) s += __shfl_xor(s, mm, 64);
        if (lane == 0) {
          float logit = __fadd_rn(s, b_out[v]);
          float key   = __fadd_rn(logit,
                          gumbel_exact(rbits(g0, g1, (unsigned)b, (unsigned)v)));
          cand_key[c] = key; cand_lg[c] = logit;
        }
      }
      __syncthreads();
      if (tid == 0) {
        float bk = -INFINITY; int bv = V; float bl = 0.0f;
        for (int c = 0; c < nc; c++) {
          float k = cand_key[c]; int v = cand[c];
          if (k > bk || (k == bk && v < bv)) { bk = k; bv = v; bl = cand_lg[c]; }
        }
        s_samp = bv; s_blog = bl;
      }
    }
  }
  __syncthreads();
  const int sampled = s_samp;
  if (tid == 0) {
    float lse = (float)log((double)SUM);
    float lp  = __fsub_rn(__fsub_rn(s_blog, M), lse);
    out_samples[b*S + t] = (float)sampled;
    out_lps[b*S + t]     = lp;
  }
  x[b*E + tid] = emb[sampled*E + tid];
}

} // namespace

extern "C" void kernel_launch(void* const* d_in, const int* in_sizes, int n_in,
                              void* d_out, int out_size, void* d_ws, size_t ws_size,
                              hipStream_t stream) {
  (void)in_sizes; (void)n_in; (void)out_size;
  const float* emb   = (const float*)d_in[0];
  const float* w_ih  = (const float*)d_in[1];
  const float* w_hh  = (const float*)d_in[2];
  const float* b_ih  = (const float*)d_in[3];
  const float* b_hh  = (const float*)d_in[4];
  const float* w_out = (const float*)d_in[5];
  const float* b_out = (const float*)d_in[6];
  float* out = (float*)d_out;

  char* wsb = (char*)d_ws;
  size_t off = 0;
  auto alloc = [&](size_t nbytes) {
    char* p = wsb + off;
    off += (nbytes + 255) & ~size_t(255);
    return p;
  };
  float* h     = (float*)alloc((size_t)B*H*4);
  float* x     = (float*)alloc((size_t)B*E*4);
  float* gi    = (float*)alloc((size_t)B*G3*4);
  float* gh    = (float*)alloc((size_t)B*G3*4);
  unsigned short* h_sw = (unsigned short*)alloc((size_t)B*H*2);
  unsigned short* w_sw = (unsigned short*)alloc((size_t)V*H*2);
  float* pmax  = (float*)alloc((size_t)B*NCH*4);
  float* psum  = (float*)alloc((size_t)B*NCH*4);
  float* plog  = (float*)alloc((size_t)B*4);
  unsigned* kq = (unsigned*)alloc((size_t)S*2*4);
  unsigned* ke = (unsigned*)alloc((size_t)S*2*4);
  unsigned char* draws = (unsigned char*)alloc((size_t)S*B);
  int* pre     = (int*)alloc((size_t)S*B*4);
  int* nd_slot = (int*)alloc((size_t)S*B*4);
  float* nd_keys = (float*)alloc((size_t)NDMAX*V*4);
  float* nd_kmax = (float*)alloc((size_t)NDMAX*NCH*4);
  if (off > ws_size) {
    fprintf(stderr, "kernel_launch: workspace too small (need %zu, have %zu)\n",
            off, ws_size);
    return;
  }

  k_init_rng<<<1, S, 0, stream>>>(kq, ke);
  k_init_draws<<<S, B, 0, stream>>>(ke, draws);
  k_init_nd<<<S, 64, 0, stream>>>(draws, nd_slot);
  k_pre_argmax<<<(S*B)/4, 256, 0, stream>>>(kq, draws, pre);
  k_init_state<<<B, 256, 0, stream>>>(emb, x, h);
  k_cast_w<<<(V*H/8)/256, 256, 0, stream>>>(w_out, w_sw);

  for (int t = 0; t < S; t++) {
    k_gates<<<dim3(G3/64, B/64, 2), 256, 0, stream>>>(x, h, w_ih, w_hh,
                                                      b_ih, b_hh, gi, gh);
    k_gru_update<<<(B*H/8)/256, 256, 0, stream>>>(gi, gh, h, h_sw);
    k_mfma_logits<<<dim3(V/VBLK, B/BBLK), 256, 0, stream>>>(
        h_sw, w_sw, b_out, kq, pre + t*B, nd_slot + t*B,
        pmax, psum, plog, nd_keys, nd_kmax, t);
    k_finish<<<B, 256, 0, stream>>>(pmax, psum, plog, pre + t*B, nd_slot + t*B,
                                    nd_keys, nd_kmax, kq, h, w_out, b_out,
                                    emb, x, out, out + (size_t)B*S, t);
  }
}